// Round 9
// baseline (326.027 us; speedup 1.0000x reference)
//
#include <hip/hip_runtime.h>
#include <hip/hip_bf16.h>
#include <cstdint>

#define B_ 8
#define T_ 2048
#define E_ 256
#define K_ 512
#define KS_ 9
#define L_ 8192
#define PAD_ 4
#define TP_ (T_ + 2 * PAD_)   // 2056
#define KK_ (E_ * KS_)        // 2304

// fp8 scaling: feats stored as fp8*64, U/final stored as fp8*16.
// S and V accumulators are 1024x true value -> multiply by 2^-10 in epilogue.
#define FEAT_SCALE 64.0f
#define W_SCALE 16.0f
#define INV_SS 9.765625e-4f         // 2^-10
#define INV_SS_LOG2E 1.40888719e-3f // 2^-10 * log2(e)

// merged-prep block ranges
#define NB_EMBED ((B_ * TP_ * 64) / 256)          // 4112
#define NB_WT ((K_ * KK_) / 256)                  // 4608
#define NB_CAST 2048                              // 2 matrices x 8192 l x 32 units / 256

typedef __bf16 bf16x8 __attribute__((ext_vector_type(8)));
typedef float f32x4 __attribute__((ext_vector_type(4)));
typedef float f32x16 __attribute__((ext_vector_type(16)));
typedef int i32x4 __attribute__((ext_vector_type(4)));
typedef int i32x8 __attribute__((ext_vector_type(8)));

__device__ __forceinline__ unsigned short f2bf(float f) {
  union { float f; unsigned int u; } a; a.f = f;
  unsigned int r = (a.u + 0x7FFFu + ((a.u >> 16) & 1u)) >> 16;
  return (unsigned short)r;
}

__device__ __forceinline__ unsigned char f2fp8(float v) {
  return (unsigned char)(__builtin_amdgcn_cvt_pk_fp8_f32(v, v, 0, false) & 0xFF);
}

__device__ __forceinline__ unsigned int pk4_fp8(float a, float b, float c, float d) {
  int v = __builtin_amdgcn_cvt_pk_fp8_f32(a, b, 0, false);
  v = __builtin_amdgcn_cvt_pk_fp8_f32(c, d, v, true);
  return (unsigned int)v;
}

__device__ __forceinline__ void gld_lds16(const void* g, void* l) {
  __builtin_amdgcn_global_load_lds(
      (const __attribute__((address_space(1))) unsigned int*)g,
      (__attribute__((address_space(3))) unsigned int*)l, 16, 0, 0);
}

// 32x32x16 bf16 MFMA: 2x the FLOP per fragment byte of 16x16x32.
__device__ __forceinline__ f32x16 mfma32_bf16(bf16x8 a, bf16x8 b, f32x16 c) {
  return __builtin_amdgcn_mfma_f32_32x32x16_bf16(a, b, c, 0, 0, 0);
}

// MX-scaled fp8 MFMA, K=64, unity e8m0 scales (0x7F -> 2^0). 2x non-scaled rate.
__device__ __forceinline__ f32x16 mfma_sc64(i32x8 a, i32x8 b, f32x16 c) {
  return __builtin_amdgcn_mfma_scale_f32_32x32x64_f8f6f4(a, b, c, 0, 0, 0, 127, 0, 127);
}

// K-unit-major (16B) layouts — the HW-verified conflict-free pattern (R3:
// SQ_LDS_BANK_CONFLICT 8.9M -> 0). Fragment reads: 32 lanes x 16B contiguous.
// feats per batch: [tc = t>>6][u = k>>4][t&63][k&15]  (32 KB per t-chunk)
__device__ __forceinline__ int f_off(int t, int k) {
  return ((t >> 6) * 32768) + (((k >> 4) * 64 + (t & 63)) << 4) + (k & 15);
}
// U/W: [lb = l>>7][u = k>>4][l&127][k&15]  (64 KB per l-block)
__device__ __forceinline__ int w_off(int l, int k) {
  return ((l >> 7) * 65536) + (((k >> 4) * 128 + (l & 127)) << 4) + (k & 15);
}

// ---------------- merged prep: embed-gather | conv_w transpose | U/F cast ----
__global__ __launch_bounds__(256) void k_prep(const int* __restrict__ ids,
                                              const float* __restrict__ emb,
                                              const float* __restrict__ conv_w,
                                              const float* __restrict__ U_w,
                                              const float* __restrict__ F_w,
                                              unsigned short* __restrict__ xpad,
                                              unsigned short* __restrict__ wt,
                                              unsigned char* __restrict__ u8,
                                              unsigned char* __restrict__ f8) {
  const int bx = blockIdx.x;
  const int tid = threadIdx.x;
  if (bx < NB_EMBED) {
    // ---- embed gather + zero halo, cast to bf16 ----
    int gid = bx * 256 + tid;
    int row = gid >> 6;
    int e4 = (gid & 63) << 2;
    int b = row / TP_;
    int tp = row - b * TP_;
    float4 v = make_float4(0.f, 0.f, 0.f, 0.f);
    if (tp >= PAD_ && tp < T_ + PAD_) {
      int id = ids[b * T_ + tp - PAD_];
      v = *(const float4*)(emb + (size_t)id * E_ + e4);
    }
    ushort4 o;
    o.x = f2bf(v.x); o.y = f2bf(v.y); o.z = f2bf(v.z); o.w = f2bf(v.w);
    *(ushort4*)(xpad + (size_t)row * E_ + e4) = o;
  } else if (bx < NB_EMBED + NB_WT) {
    // ---- conv_w [K,E,KS] -> W_t [K][j*256+e] bf16 ----
    int g = (bx - NB_EMBED) * 256 + tid;
    int k = g / KK_;
    int kk = g - k * KK_;
    int j = kk >> 8, e = kk & 255;
    wt[(size_t)k * KK_ + kk] = f2bf(conv_w[(k * E_ + e) * KS_ + j]);
  } else {
    // ---- U_w / final_w fp32 -> fp8 (x16), K-unit-major, COALESCED writes:
    // lane owns one full 16B unit of one l; consecutive lanes = consecutive l
    // -> wave writes 1024 B contiguous (was 8 B per lane at 2 KB stride).
    int g = (bx - NB_EMBED - NB_WT) * 256 + tid;   // 0 .. 2^19-1
    int sel = g >> 18;                              // 0 = U, 1 = F
    int gi = g & ((1 << 18) - 1);
    int u = (gi >> 6) & 31;
    int l = ((gi >> 11) << 6) | (gi & 63);
    const float* src = sel ? F_w : U_w;
    unsigned char* dst = sel ? f8 : u8;
    const float* s = src + (size_t)l * K_ + u * 16;
    float4 v0 = *(const float4*)(s);
    float4 v1 = *(const float4*)(s + 4);
    float4 v2 = *(const float4*)(s + 8);
    float4 v3 = *(const float4*)(s + 12);
    uint4 o;
    o.x = pk4_fp8(v0.x * W_SCALE, v0.y * W_SCALE, v0.z * W_SCALE, v0.w * W_SCALE);
    o.y = pk4_fp8(v1.x * W_SCALE, v1.y * W_SCALE, v1.z * W_SCALE, v1.w * W_SCALE);
    o.z = pk4_fp8(v2.x * W_SCALE, v2.y * W_SCALE, v2.z * W_SCALE, v2.w * W_SCALE);
    o.w = pk4_fp8(v3.x * W_SCALE, v3.y * W_SCALE, v3.z * W_SCALE, v3.w * W_SCALE);
    *(uint4*)(dst + w_off(l, u * 16)) = o;
  }
}

// ---------------- conv1d as MFMA GEMM, REBUILT ----------------
// R8 analysis: old k_conv ran at ~25% of its LDS roofline (~100-120 us,
// bounded above by k_attn's 126 in the top-5). Three fixes, all patterns
// HW-verified elsewhere in this session:
//  (1) 32x32x16 bf16 MFMA with 64x64 output per wave: 16 MFMA + 16 b128
//      reads per wave-iter = 32 FLOP/LDS-byte (was 21).
//  (2) K-unit-major LDS tiles [u][row][16B] for A and B: fragment reads are
//      32 lanes x 16B contiguous (R3's zero-conflict pattern); staging stays
//      linear for global_load_lds. Conv sliding window folded into the
//      staging source address (A[t][kk] = xpad[t0+t+(kk>>8)][kk&255]).
//  (3) 256-thread blocks (4 waves, 2x2 wave grid), 64 KB LDS -> 2 blocks/CU:
//      cross-block overlap decouples barrier phases; cheaper syncs.
__global__ __launch_bounds__(256, 2) void k_conv(const unsigned short* __restrict__ xpad,
                                                 const unsigned short* __restrict__ wt,
                                                 const float* __restrict__ conv_b,
                                                 unsigned char* __restrict__ feats) {
  __shared__ __align__(16) char sm[2][32768];   // [buf][A 16K | B 16K]
  const int tid = threadIdx.x;
  const int lane = tid & 63;
  const int q2 = lane >> 5, c32 = lane & 31;
  const int w = tid >> 6;
  const int wt_i = w >> 1;  // t half (64 rows)
  const int wn = w & 1;     // n half (64 cols)
  const int b = blockIdx.z;
  const int t0 = blockIdx.y * 128;
  const int n0 = blockIdx.x * 128;

  const char* xb = (const char*)(xpad + (size_t)b * TP_ * E_);
  const char* wb = (const char*)wt;

  // staging precompute: 8 x 16B per thread (4 A rounds, 4 B rounds).
  // dest d = r*4096 + tid*16 -> u = d>>11 (K-unit), row = (d>>4)&127.
  const char* aptr[4]; int au8[4];
  const char* bptr[4];
#pragma unroll
  for (int r = 0; r < 4; ++r) {
    int d = r * 4096 + tid * 16;
    int u = d >> 11;
    int row = (d >> 4) & 127;
    aptr[r] = xb + (size_t)(t0 + row) * 512;
    au8[r] = u * 8;
    bptr[r] = wb + (size_t)(n0 + row) * (KK_ * 2) + u * 16;
  }
  const int ldso = tid * 16;

#define STAGE(BUF, KKC)                                                    \
  {                                                                        \
    _Pragma("unroll") for (int r = 0; r < 4; ++r) {                        \
      int kkg = (KKC) + au8[r];                                            \
      int j = kkg >> 8, e0 = kkg & 255;                                    \
      gld_lds16(aptr[r] + j * 512 + e0 * 2, (BUF) + r * 4096 + ldso);      \
    }                                                                      \
    _Pragma("unroll") for (int r = 0; r < 4; ++r)                          \
      gld_lds16(bptr[r] + (KKC) * 2, (BUF) + 16384 + r * 4096 + ldso);     \
  }

  f32x16 acc00, acc01, acc10, acc11;
#pragma unroll
  for (int r = 0; r < 16; ++r) { acc00[r] = 0.f; acc01[r] = 0.f; acc10[r] = 0.f; acc11[r] = 0.f; }

  STAGE(sm[0], 0)

  const int aoff0 = (wt_i * 64 + c32) * 16;
  const int boff0 = 16384 + (wn * 64 + c32) * 16;

  for (int it = 0; it < 36; ++it) {
    __syncthreads();
    if (it != 35) STAGE(sm[(it + 1) & 1], (it + 1) * 64)
    const char* buf = sm[it & 1];
#pragma unroll
    for (int ks = 0; ks < 4; ++ks) {
      const char* base = buf + (ks * 2 + q2) * 2048;
      bf16x8 a0 = *(const bf16x8*)(base + aoff0);
      bf16x8 a1 = *(const bf16x8*)(base + aoff0 + 512);
      bf16x8 b0 = *(const bf16x8*)(base + boff0);
      bf16x8 b1 = *(const bf16x8*)(base + boff0 + 512);
      acc00 = mfma32_bf16(a0, b0, acc00);
      acc01 = mfma32_bf16(a0, b1, acc01);
      acc10 = mfma32_bf16(a1, b0, acc10);
      acc11 = mfma32_bf16(a1, b1, acc11);
    }
  }
#undef STAGE

  // epilogue: +bias, relu, fp8 store into the K-unit-major feats layout.
  // C/D 32x32: col = lane&31, row = (r&3) + 8*(r>>2) + 4*(lane>>5).
  const size_t fbase = (size_t)b * T_ * K_;
  const float bias0 = conv_b[n0 + wn * 64 + c32];
  const float bias1 = conv_b[n0 + wn * 64 + 32 + c32];
#define EPI(ACC, TA, TB, BIAS)                                              \
  {                                                                         \
    _Pragma("unroll") for (int r = 0; r < 16; ++r) {                        \
      int trow = t0 + wt_i * 64 + (TA) * 32 + (r & 3) + 8 * (r >> 2) + 4 * q2; \
      int k = n0 + wn * 64 + (TB) * 32 + c32;                               \
      float v = fmaxf(ACC[r] + (BIAS), 0.f) * FEAT_SCALE;                   \
      feats[fbase + f_off(trow, k)] = f2fp8(v);                             \
    }                                                                       \
  }
  EPI(acc00, 0, 0, bias0)
  EPI(acc01, 0, 1, bias1)
  EPI(acc10, 1, 0, bias0)
  EPI(acc11, 1, 1, bias1)
#undef EPI
}

// ---------------- fused label-attention ----------------
// EXACT R3 structure — best measured (124.2 us, MfmaUtil 48%, 0 conflicts,
// no spill). R8's zero-C variant was consistently +2 us: reverted. CLOSED
// axes (measured): dual-acc softmax shadow (R4/5/6), counted-vmcnt ring
// (R4), pair-barrier coarsening (R7). Occupancy is register-pinned at
// 2 waves/SIMD by the 128-reg uf/wf fragment mass.
__global__ __launch_bounds__(512, 2) void k_attn(const unsigned char* __restrict__ feats,
                                                 const unsigned char* __restrict__ u8,
                                                 const unsigned char* __restrict__ f8,
                                                 const float* __restrict__ final_b,
                                                 float* __restrict__ out) {
  __shared__ __align__(16) char smem[131072];
  __shared__ float red[512];
  const int tid = threadIdx.x;
  const int lane = tid & 63;
  const int q2 = lane >> 5, c32 = lane & 31;
  const int w = tid >> 6;
  const int wi = w >> 1;   // L quarter (32 rows)
  const int wj = w & 1;    // T half (32 cols of the 64-col chunk)
  const int b = blockIdx.y;
  const int l0 = blockIdx.x * 128;

  const unsigned char* fb = feats + (size_t)b * T_ * K_;

  // ---- stage U/W (K-unit-major) identity into LDS: 64 KB each ----
  char* Us = smem;
  char* Ws = smem + 65536;
#pragma unroll
  for (int rr = 0; rr < 8; ++rr) {
    gld_lds16(u8 + (size_t)l0 * K_ + rr * 8192 + tid * 16, Us + rr * 8192 + tid * 16);
    gld_lds16(f8 + (size_t)l0 * K_ + rr * 8192 + tid * 16, Ws + rr * 8192 + tid * 16);
  }
  __syncthreads();

  // ---- pull full-K A-fragments into registers: 8 K-blocks x 32B each ----
  const int arow = wi * 32 + c32;
  const int abase = q2 * 4096 + arow * 16;
  i32x8 uf[8], wf[8];
#pragma unroll
  for (int s = 0; s < 8; ++s) {
    int o0 = abase + s * 8192;
    i32x4 ul = *(const i32x4*)(Us + o0);
    i32x4 uh = *(const i32x4*)(Us + o0 + 2048);
    i32x4 wl = *(const i32x4*)(Ws + o0);
    i32x4 wh = *(const i32x4*)(Ws + o0 + 2048);
    uf[s] = __builtin_shufflevector(ul, uh, 0, 1, 2, 3, 4, 5, 6, 7);
    wf[s] = __builtin_shufflevector(wl, wh, 0, 1, 2, 3, 4, 5, 6, 7);
  }
  __syncthreads();   // all waves done reading before F overwrites this region

  // ---- F double-buffer in the same LDS: 2 x 32 KB ([u][64][16] per chunk) ----
  char* const Fs0 = smem;
  char* const Fs1 = smem + 32768;
  const unsigned char* fsrc = fb + tid * 16;   // + tc*32768 + rr*8192
#pragma unroll
  for (int rr = 0; rr < 4; ++rr)
    gld_lds16(fsrc + rr * 8192, Fs0 + tid * 16 + rr * 8192);

  const int brow = wj * 32 + c32;
  const int bbase = q2 * 2048 + brow * 16;

  f32x16 accS, accV;
  float num[16], den[16];
#pragma unroll
  for (int r = 0; r < 16; ++r) { accS[r] = 0.f; accV[r] = 0.f; num[r] = 0.f; den[r] = 0.f; }

  for (int tc = 0; tc < 32; ++tc) {
    const int bsel = tc & 1;
    char* const cur = bsel ? Fs1 : Fs0;
    char* const nxt = bsel ? Fs0 : Fs1;
    __syncthreads();   // chunk tc staged; prior reads of the other buffer done
    if (tc != 31) {
      const unsigned char* nsrc = fsrc + (size_t)(tc + 1) * 32768;
#pragma unroll
      for (int rr = 0; rr < 4; ++rr)
        gld_lds16(nsrc + rr * 8192, nxt + tid * 16 + rr * 8192);
    }
#pragma unroll
    for (int s = 0; s < 8; ++s) {
      i32x4 flo = *(const i32x4*)(cur + bbase + s * 4096);
      i32x4 fhi = *(const i32x4*)(cur + bbase + s * 4096 + 1024);
      i32x8 fa = __builtin_shufflevector(flo, fhi, 0, 1, 2, 3, 4, 5, 6, 7);
      accS = mfma_sc64(uf[s], fa, accS);
      accV = mfma_sc64(wf[s], fa, accV);
    }
    // softmax-weighted accumulate, reset. scores O(0.01): no max-shift needed.
#pragma unroll
    for (int r = 0; r < 16; ++r) {
      float p = __builtin_exp2f(accS[r] * INV_SS_LOG2E);
      den[r] += p;
      num[r] += p * accV[r];
      accS[r] = 0.f;
      accV[r] = 0.f;
    }
  }

  // reduce over 32 t-columns (c32 lanes; q2 halves hold different L-rows)
#pragma unroll
  for (int r = 0; r < 16; ++r) {
#pragma unroll
    for (int m = 1; m < 32; m <<= 1) {
      num[r] += __shfl_xor(num[r], m, 64);
      den[r] += __shfl_xor(den[r], m, 64);
    }
  }
  if (c32 == 0) {
#pragma unroll
    for (int r = 0; r < 16; ++r) {
      int ll = wi * 32 + (r & 3) + 8 * (r >> 2) + 4 * q2;
      red[wj * 256 + ll] = num[r];
      red[wj * 256 + 128 + ll] = den[r];
    }
  }
  __syncthreads();
  if (tid < 128) {
    int l = l0 + tid;
    float n = red[tid] + red[256 + tid];
    float d = red[128 + tid] + red[384 + tid];
    out[(size_t)b * L_ + l] = (n * INV_SS) / d + final_b[l];
  }
}

// ---------------- BCE-with-logits mean ----------------
__global__ __launch_bounds__(256) void k_loss(const float* __restrict__ yhat,
                                              const float* __restrict__ target,
                                              float* __restrict__ loss) {
  int gid = blockIdx.x * 256 + threadIdx.x;
  float s = 0.f;
  for (int i = gid; i < B_ * L_; i += 64 * 256) {
    float y = yhat[i], t = target[i];
    s += fmaxf(y, 0.f) - y * t + log1pf(__expf(-fabsf(y)));
  }
#pragma unroll
  for (int m = 1; m < 64; m <<= 1) s += __shfl_xor(s, m, 64);
  if ((threadIdx.x & 63) == 0) atomicAdd(loss, s * (1.0f / (B_ * L_)));
}

extern "C" void kernel_launch(void* const* d_in, const int* in_sizes, int n_in,
                              void* d_out, int out_size, void* d_ws, size_t ws_size,
                              hipStream_t stream) {
  const int* ids = (const int*)d_in[0];
  const float* target = (const float*)d_in[3];
  const float* emb = (const float*)d_in[4];
  const float* conv_w = (const float*)d_in[5];
  const float* conv_b = (const float*)d_in[6];
  const float* U_w = (const float*)d_in[7];
  const float* F_w = (const float*)d_in[8];
  const float* final_b = (const float*)d_in[9];
  float* out = (float*)d_out;

  char* ws = (char*)d_ws;
  unsigned short* xpad = (unsigned short*)ws;                    // bf16 B*TP*E
  size_t off = (size_t)B_ * TP_ * E_ * 2;
  unsigned short* wt = (unsigned short*)(ws + off);              // bf16 K*KK
  off += (size_t)K_ * KK_ * 2;
  unsigned char* u8 = (unsigned char*)(ws + off);                // fp8 L*K (unit-major)
  off += (size_t)L_ * K_;
  unsigned char* f8 = (unsigned char*)(ws + off);                // fp8 L*K (unit-major)
  off += (size_t)L_ * K_;
  unsigned char* feats = (unsigned char*)(ws + off);             // fp8 B*T*K (unit-major)
  off += (size_t)B_ * T_ * K_;
  if (ws_size < off) return;

  k_prep<<<dim3(NB_EMBED + NB_WT + NB_CAST), 256, 0, stream>>>(
      ids, emb, conv_w, U_w, F_w, xpad, wt, u8, f8);
  hipMemsetAsync(out + B_ * L_, 0, sizeof(float), stream);
  k_conv<<<dim3(K_ / 128, T_ / 128, B_), 256, 0, stream>>>(xpad, wt, conv_b, feats);
  k_attn<<<dim3(L_ / 128, B_), 512, 0, stream>>>(feats, u8, f8, final_b, out);
  k_loss<<<dim3(64), 256, 0, stream>>>(out, target, out + B_ * L_);
}